// Round 8
// baseline (1547.843 us; speedup 1.0000x reference)
//
#include <hip/hip_runtime.h>
#include <hip/hip_fp16.h>
#include <math.h>

// Problem constants (match reference)
constexpr int NN = 50000;    // nodes
constexpr int NE = 800000;   // undirected edges E0
constexpr int KS = 10;       // iterations
constexpr float LAM = 3.0f;  // lambda

constexpr int SCAN_NB = (NN + 255) / 256;  // 196 scan blocks
constexpr int NODE_NB = NN * 64 / 256;     // 12500 one-wave-per-node blocks

// ---------------- precompute kernels ----------------

__global__ __launch_bounds__(256) void countRC_kernel(
    const int* __restrict__ src, const int* __restrict__ dst,
    int* __restrict__ cR, int* __restrict__ cC) {
  int e = blockIdx.x * 256 + threadIdx.x;
  if (e >= NE) return;
  int s = src[e], d = dst[e];
  int r = s > d ? s : d;
  int c = s > d ? d : s;
  atomicAdd(&cR[r], 1);
  atomicAdd(&cC[c], 1);
}

__global__ __launch_bounds__(256) void dis_kernel(
    const int* __restrict__ cR, const int* __restrict__ cC,
    float* __restrict__ dis) {
  int i = blockIdx.x * 256 + threadIdx.x;
  if (i < NN) dis[i] = 1.0f / sqrtf((float)(cR[i] + cC[i] + 1));
}

// fp16 SPLIT shadow of x: XHlo holds features 0-31, XHhi 32-63 (3.2 MB each)
__global__ __launch_bounds__(256) void half_copy_kernel(
    const float* __restrict__ X, __half* __restrict__ XHlo,
    __half* __restrict__ XHhi) {
  int i = blockIdx.x * 256 + threadIdx.x;  // float4 units
  if (i >= NN * 16) return;
  float4 v = ((const float4*)X)[i];
  __half2 h0 = __floats2half2_rn(v.x, v.y);
  __half2 h1 = __floats2half2_rn(v.z, v.w);
  uint2 o;
  o.x = *(const unsigned*)&h0;
  o.y = *(const unsigned*)&h1;
  int w = i >> 4, f4 = i & 15;
  __half* dst = (f4 < 8) ? XHlo : XHhi;
  ((uint2*)dst)[w * 8 + (f4 & 7)] = o;
}

// ---- hierarchical exclusive scan: A) block sums, B) scan sums, C) emit ----

__global__ __launch_bounds__(256) void scanA_kernel(
    const int* __restrict__ cnt, int* __restrict__ bsum) {
  __shared__ int sm[256];
  int t = threadIdx.x;
  int i = blockIdx.x * 256 + t;
  int v = (i < NN) ? cnt[i] : 0;
  sm[t] = v;
  __syncthreads();
  for (int off = 128; off > 0; off >>= 1) {
    if (t < off) sm[t] += sm[t + off];
    __syncthreads();
  }
  if (t == 0) bsum[blockIdx.x] = sm[0];
}

__global__ __launch_bounds__(256) void scanB_kernel(
    int* __restrict__ bsum, int* __restrict__ boff) {
  __shared__ int sm[256];
  int t = threadIdx.x;
  int v = (t < SCAN_NB) ? bsum[t] : 0;
  sm[t] = v;
  __syncthreads();
  for (int off = 1; off < 256; off <<= 1) {
    int a = (t >= off) ? sm[t - off] : 0;
    __syncthreads();
    sm[t] += a;
    __syncthreads();
  }
  if (t < SCAN_NB) boff[t] = sm[t] - v;  // exclusive
}

__global__ __launch_bounds__(256) void scanC_kernel(
    const int* __restrict__ cnt, const int* __restrict__ boff,
    int* __restrict__ ptr, int* __restrict__ cur) {
  __shared__ int sm[256];
  int t = threadIdx.x;
  int i = blockIdx.x * 256 + t;
  int v = (i < NN) ? cnt[i] : 0;
  sm[t] = v;
  __syncthreads();
  for (int off = 1; off < 256; off <<= 1) {
    int a = (t >= off) ? sm[t - off] : 0;
    __syncthreads();
    sm[t] += a;
    __syncthreads();
  }
  if (i < NN) {
    int ex = boff[blockIdx.x] + sm[t] - v;  // exclusive prefix
    ptr[i] = ex;
    cur[i] = ex;
    if (i == NN - 1) ptr[NN] = ex + v;
  }
}

// Counting-sort scatter: new edge id p = position in r-sorted order.
// cb8[p] = (c, dis[c]) 8B; c-side CSR entry (r, p) for node c.
__global__ __launch_bounds__(256) void sortscatter_kernel(
    const int* __restrict__ src, const int* __restrict__ dst,
    const float* __restrict__ dis,
    int* __restrict__ urR, int* __restrict__ uC,
    int2* __restrict__ cb8, int2* __restrict__ cEnt) {
  int e = blockIdx.x * 256 + threadIdx.x;
  if (e >= NE) return;
  int s = src[e], d = dst[e];
  int r = s > d ? s : d;
  int c = s > d ? d : s;
  int p = atomicAdd(&urR[r], 1);
  cb8[p] = make_int2(c, __float_as_int(dis[c]));
  int q = atomicAdd(&uC[c], 1);
  cEnt[q] = make_int2(r, p);
}

// ---------------- per-step kernels ----------------

// adj: y = 0.25*h + 0.75*(D^-1/2 (A+I) D^-1/2) xk ; XB = y - 0.25*U_old.
// FEATURE-SPLIT: grid = 2*NODE_NB; blocks [0,NODE_NB) do features 0-31
// (gather XHlo, 3.2 MB ~ L2-resident), the rest features 32-63 (XHhi).
// Per wave: 8 groups x 8 lanes; lane l covers 4 feats (8B fp16); unified
// branch-free r-side/c-side walk, x2 unrolled.
template <int FIRST>
__global__ __launch_bounds__(256) void adj_kernel(
    const __half* __restrict__ XHlo, const __half* __restrict__ XHhi,
    const float* __restrict__ H, const float* __restrict__ U,
    const float* __restrict__ dis,
    const int* __restrict__ rPtr, const int* __restrict__ cPtr,
    const int2* __restrict__ cEnt, const int2* __restrict__ cb8,
    float* __restrict__ XB, __half* __restrict__ XBh) {
  int bid = blockIdx.x;
  int half = (bid >= NODE_NB) ? 1 : 0;
  int w = (int)(((unsigned)(bid - half * NODE_NB) * 256u + threadIdx.x) >> 6);
  if (w >= NN) return;
  int lane = threadIdx.x & 63;
  int g = lane >> 3, l = lane & 7;
  const uint2* XH2 = (const uint2*)(half ? XHhi : XHlo);
  int rb = rPtr[w], lenR = rPtr[w + 1] - rb;
  int cb = cPtr[w], lenC = cPtr[w + 1] - cb;
  int total = lenR + lenC;
  int lr1 = lenR > 0 ? lenR - 1 : 0;
  int lc1 = lenC > 0 ? lenC - 1 : 0;
  float ax = 0.f, ay = 0.f, az = 0.f, aw = 0.f;

#define ADJ_FETCH(T, NB, WT)                                         \
  {                                                                  \
    int tr = (T) < lr1 ? (T) : lr1;                                  \
    int tc = (T) - lenR; tc = tc > 0 ? tc : 0; tc = tc < lc1 ? tc : lc1; \
    int2 rcv = cb8[rb + tr];                                         \
    int2 ce = cEnt[cb + tc];                                         \
    bool isR = (T) < lenR;                                           \
    NB = isR ? rcv.x : ce.x;                                         \
    WT = isR ? __int_as_float(rcv.y) : dis[ce.x];                    \
  }
#define ADJ_ACC(XV, W)                                               \
  {                                                                  \
    float2 p = __half22float2(*(const __half2*)&XV.x);               \
    float2 q = __half22float2(*(const __half2*)&XV.y);               \
    ax = fmaf(W, p.x, ax); ay = fmaf(W, p.y, ay);                    \
    az = fmaf(W, q.x, az); aw = fmaf(W, q.y, aw);                    \
  }

  int t = g;
  for (; t + 8 < total; t += 16) {
    int n0, n1; float w0, w1;
    ADJ_FETCH(t, n0, w0);
    ADJ_FETCH(t + 8, n1, w1);
    uint2 x0 = XH2[n0 * 8 + l];
    uint2 x1 = XH2[n1 * 8 + l];
    ADJ_ACC(x0, w0);
    ADJ_ACC(x1, w1);
  }
  for (; t < total; t += 8) {
    int n0; float w0;
    ADJ_FETCH(t, n0, w0);
    uint2 x0 = XH2[n0 * 8 + l];
    ADJ_ACC(x0, w0);
  }
#undef ADJ_FETCH
#undef ADJ_ACC

  ax += __shfl_xor(ax, 8, 64); ay += __shfl_xor(ay, 8, 64);
  az += __shfl_xor(az, 8, 64); aw += __shfl_xor(aw, 8, 64);
  ax += __shfl_xor(ax, 16, 64); ay += __shfl_xor(ay, 16, 64);
  az += __shfl_xor(az, 16, 64); aw += __shfl_xor(aw, 16, 64);
  ax += __shfl_xor(ax, 32, 64); ay += __shfl_xor(ay, 32, 64);
  az += __shfl_xor(az, 32, 64); aw += __shfl_xor(aw, 32, 64);
  if (g == 0) {
    float di = dis[w];
    int idx = w * 16 + half * 8 + l;   // float4 / uint2 index in full row
    uint2 xsu = XH2[w * 8 + l];        // self term from fp16 shadow
    float2 xsa = __half22float2(*(const __half2*)&xsu.x);
    float2 xsb = __half22float2(*(const __half2*)&xsu.y);
    float4 h4 = ((const float4*)H)[idx];
    float4 y4;
    y4.x = 0.25f * h4.x + 0.75f * di * fmaf(di, xsa.x, ax);
    y4.y = 0.25f * h4.y + 0.75f * di * fmaf(di, xsa.y, ay);
    y4.z = 0.25f * h4.z + 0.75f * di * fmaf(di, xsb.x, az);
    y4.w = 0.25f * h4.w + 0.75f * di * fmaf(di, xsb.y, aw);
    float4 xb;
    if (FIRST) {
      xb = y4;
    } else {
      float4 u4 = ((const float4*)U)[idx];
      xb.x = y4.x - 0.25f * u4.x;
      xb.y = y4.y - 0.25f * u4.y;
      xb.z = y4.z - 0.25f * u4.z;
      xb.w = y4.w - 0.25f * u4.w;
    }
    ((float4*)XB)[idx] = xb;
    __half2 hb0 = __floats2half2_rn(xb.x, xb.y);
    __half2 hb1 = __floats2half2_rn(xb.z, xb.w);
    uint2 ob;
    ob.x = *(const unsigned*)&hb0;
    ob.y = *(const unsigned*)&hb1;
    ((uint2*)XBh)[idx] = ob;
  }
}

// K1 zupd: per node w, walk its contiguous r-side edge range [rb,re):
// z' = proj_L21(z + 2*(dis[w]*xb[w] - b*xb[c])), write Z in place, and
// accumulate U1[w] = sum_r z' (fused r-side of incT — no Z re-read).
template <int FIRST>
__global__ __launch_bounds__(256) void zupd_kernel(
    __half* __restrict__ Z, const __half* __restrict__ XBh,
    const float* __restrict__ dis,
    const int* __restrict__ rPtr, const int2* __restrict__ cb8,
    float* __restrict__ U1) {
  int w = (int)((blockIdx.x * 256u + threadIdx.x) >> 6);
  if (w >= NN) return;
  int lane = threadIdx.x & 63;
  int g = lane >> 4, l = lane & 15;
  const uint2* X2 = (const uint2*)XBh;
  uint2* Z2 = (uint2*)Z;
  int rb = rPtr[w], re = rPtr[w + 1];
  float a = dis[w];
  uint2 xwu = X2[w * 16 + l];
  float2 xwa = __half22float2(*(const __half2*)&xwu.x);
  float2 xwb = __half22float2(*(const __half2*)&xwu.y);
  float sx = 0.f, sy = 0.f, sz = 0.f, sw = 0.f;
  for (int e = rb + g; e < re; e += 4) {
    int2 cbv = cb8[e];
    int c = cbv.x;
    float b = __int_as_float(cbv.y);
    uint2 xcu = X2[c * 16 + l];
    float2 xca = __half22float2(*(const __half2*)&xcu.x);
    float2 xcb = __half22float2(*(const __half2*)&xcu.y);
    float zx, zy, zz, zw;
    if (FIRST) {
      zx = zy = zz = zw = 0.f;   // z0 = 0 (never read poisoned ws)
    } else {
      uint2 zu = Z2[e * 16 + l];
      float2 f0 = __half22float2(*(const __half2*)&zu.x);
      float2 f1 = __half22float2(*(const __half2*)&zu.y);
      zx = f0.x; zy = f0.y; zz = f1.x; zw = f1.y;
    }
    zx += 2.0f * (a * xwa.x - b * xca.x);
    zy += 2.0f * (a * xwa.y - b * xca.y);
    zz += 2.0f * (a * xwb.x - b * xcb.x);
    zw += 2.0f * (a * xwb.y - b * xcb.y);
    float ss = zx * zx + zy * zy + zz * zz + zw * zw;
    ss += __shfl_xor(ss, 1, 64);
    ss += __shfl_xor(ss, 2, 64);
    ss += __shfl_xor(ss, 4, 64);
    ss += __shfl_xor(ss, 8, 64);   // 16-lane group sum
    float rn = sqrtf(ss);
    float sc = (rn > LAM) ? (LAM / rn) : 1.0f;
    zx *= sc; zy *= sc; zz *= sc; zw *= sc;
    __half2 o0 = __floats2half2_rn(zx, zy);
    __half2 o1 = __floats2half2_rn(zz, zw);
    uint2 outu;
    outu.x = *(const unsigned*)&o0;
    outu.y = *(const unsigned*)&o1;
    Z2[e * 16 + l] = outu;
    sx += zx; sy += zy; sz += zz; sw += zw;
  }
  sx += __shfl_xor(sx, 16, 64); sy += __shfl_xor(sy, 16, 64);
  sz += __shfl_xor(sz, 16, 64); sw += __shfl_xor(sw, 16, 64);
  sx += __shfl_xor(sx, 32, 64); sy += __shfl_xor(sy, 32, 64);
  sz += __shfl_xor(sz, 32, 64); sw += __shfl_xor(sw, 32, 64);
  if (g == 0) {
    ((float4*)U1)[w * 16 + l] = make_float4(sx, sy, sz, sw);
  }
}

// K2 cside: csum = sum_{c-side} z' (random gather); u = dis*(U1 - csum);
// y = XB + 0.25*U_old; xnew = y - 0.25*u; U <- u; XH split <- fp16(xnew)
// (LAST: write fp32 out instead).
template <int FIRST, int LAST>
__global__ __launch_bounds__(256) void cside_kernel(
    const __half* __restrict__ Z, const float* __restrict__ XB,
    const float* __restrict__ dis,
    const int* __restrict__ cPtr, const int2* __restrict__ cEnt,
    const float* __restrict__ U1, float* __restrict__ U,
    float* __restrict__ Xout, __half* __restrict__ XHlo,
    __half* __restrict__ XHhi) {
  int w = (int)((blockIdx.x * 256u + threadIdx.x) >> 6);
  if (w >= NN) return;
  int lane = threadIdx.x & 63;
  int g = lane >> 4, l = lane & 15;
  const uint2* Z2 = (const uint2*)Z;
  int cb = cPtr[w], ce = cPtr[w + 1];
  float sx = 0.f, sy = 0.f, sz = 0.f, sw = 0.f;
  int j = cb + g;
  for (; j + 12 < ce; j += 16) {
    int e0 = cEnt[j].y;
    int e1 = cEnt[j + 4].y;
    int e2 = cEnt[j + 8].y;
    int e3 = cEnt[j + 12].y;
    uint2 zu0 = Z2[e0 * 16 + l];
    uint2 zu1 = Z2[e1 * 16 + l];
    uint2 zu2 = Z2[e2 * 16 + l];
    uint2 zu3 = Z2[e3 * 16 + l];
    float2 a0 = __half22float2(*(const __half2*)&zu0.x);
    float2 b0 = __half22float2(*(const __half2*)&zu0.y);
    float2 a1 = __half22float2(*(const __half2*)&zu1.x);
    float2 b1 = __half22float2(*(const __half2*)&zu1.y);
    float2 a2 = __half22float2(*(const __half2*)&zu2.x);
    float2 b2 = __half22float2(*(const __half2*)&zu2.y);
    float2 a3 = __half22float2(*(const __half2*)&zu3.x);
    float2 b3 = __half22float2(*(const __half2*)&zu3.y);
    sx += a0.x + a1.x + a2.x + a3.x;
    sy += a0.y + a1.y + a2.y + a3.y;
    sz += b0.x + b1.x + b2.x + b3.x;
    sw += b0.y + b1.y + b2.y + b3.y;
  }
  for (; j < ce; j += 4) {
    int e0 = cEnt[j].y;
    uint2 zu0 = Z2[e0 * 16 + l];
    float2 a0 = __half22float2(*(const __half2*)&zu0.x);
    float2 b0 = __half22float2(*(const __half2*)&zu0.y);
    sx += a0.x; sy += a0.y; sz += b0.x; sw += b0.y;
  }
  sx += __shfl_xor(sx, 16, 64); sy += __shfl_xor(sy, 16, 64);
  sz += __shfl_xor(sz, 16, 64); sw += __shfl_xor(sw, 16, 64);
  sx += __shfl_xor(sx, 32, 64); sy += __shfl_xor(sy, 32, 64);
  sz += __shfl_xor(sz, 32, 64); sw += __shfl_xor(sw, 32, 64);
  if (g == 0) {
    float di = dis[w];
    int idx = w * 16 + l;
    float4 u1 = ((const float4*)U1)[idx];
    float4 u;
    u.x = di * (u1.x - sx);
    u.y = di * (u1.y - sy);
    u.z = di * (u1.z - sz);
    u.w = di * (u1.w - sw);
    float4 xb = ((const float4*)XB)[idx];
    float4 y4;
    if (FIRST) {
      y4 = xb;  // U_old == 0
    } else {
      float4 uo = ((const float4*)U)[idx];
      y4.x = xb.x + 0.25f * uo.x;
      y4.y = xb.y + 0.25f * uo.y;
      y4.z = xb.z + 0.25f * uo.z;
      y4.w = xb.w + 0.25f * uo.w;
    }
    float4 o;
    o.x = y4.x - 0.25f * u.x;
    o.y = y4.y - 0.25f * u.y;
    o.z = y4.z - 0.25f * u.z;
    o.w = y4.w - 0.25f * u.w;
    if (LAST) {
      ((float4*)Xout)[idx] = o;
    } else {
      ((float4*)U)[idx] = u;
      __half2 h0 = __floats2half2_rn(o.x, o.y);
      __half2 h1 = __floats2half2_rn(o.z, o.w);
      uint2 oh;
      oh.x = *(const unsigned*)&h0;
      oh.y = *(const unsigned*)&h1;
      __half* dst = (l < 8) ? XHlo : XHhi;
      ((uint2*)dst)[w * 8 + (l & 7)] = oh;
    }
  }
}

// ---------------- launch ----------------

extern "C" void kernel_launch(void* const* d_in, const int* in_sizes, int n_in,
                              void* d_out, int out_size, void* d_ws, size_t ws_size,
                              hipStream_t stream) {
  const float* x  = (const float*)d_in[0];
  const int* esrc = (const int*)d_in[1];
  const int* edst = (const int*)d_in[2];
  float* out = (float*)d_out;

  char* base = (char*)d_ws;
  size_t off = 0;
  auto carve = [&](size_t bytes) -> void* {
    void* p = base + off;
    off += (bytes + 255) & ~(size_t)255;
    return p;
  };
  __half* Z    = (__half*)carve((size_t)NE * 64 * 2);  // 102.4 MB carry z
  float* XB    = (float*)carve((size_t)NN * 64 * 4);   // x_bar fp32 master
  float* U     = (float*)carve((size_t)NN * 64 * 4);   // incT(z) carry
  float* U1    = (float*)carve((size_t)NN * 64 * 4);   // r-side partial sums
  __half* XHlo = (__half*)carve((size_t)NN * 32 * 2);  // xk shadow feats 0-31
  __half* XHhi = (__half*)carve((size_t)NN * 32 * 2);  // xk shadow feats 32-63
  __half* XBh  = (__half*)carve((size_t)NN * 64 * 2);  // x_bar shadow (interleaved)
  float* dis = (float*)carve((size_t)NN * 4);
  int* cR  = (int*)carve((size_t)NN * 4);
  int* cC  = (int*)carve((size_t)NN * 4);
  int* rPtr = (int*)carve((size_t)(NN + 1) * 4);
  int* cPtr = (int*)carve((size_t)(NN + 1) * 4);
  int* urR = (int*)carve((size_t)NN * 4);
  int* uC  = (int*)carve((size_t)NN * 4);
  int* bsum = (int*)carve((size_t)SCAN_NB * 4);
  int* boff = (int*)carve((size_t)SCAN_NB * 4);
  int2* cb8  = (int2*)carve((size_t)NE * 8);  // (c, dis[c]) sorted by r
  int2* cEnt = (int2*)carve((size_t)NE * 8);  // (r, p) c-side CSR
  (void)ws_size; (void)in_sizes; (void)n_in; (void)out_size;

  hipMemsetAsync(cR, 0, NN * 4, stream);
  hipMemsetAsync(cC, 0, NN * 4, stream);

  const int edgeGrid = (NE + 255) / 256;
  countRC_kernel<<<edgeGrid, 256, 0, stream>>>(esrc, edst, cR, cC);
  dis_kernel<<<(NN + 255) / 256, 256, 0, stream>>>(cR, cC, dis);
  half_copy_kernel<<<(NN * 16 + 255) / 256, 256, 0, stream>>>(x, XHlo, XHhi);
  scanA_kernel<<<SCAN_NB, 256, 0, stream>>>(cR, bsum);
  scanB_kernel<<<1, 256, 0, stream>>>(bsum, boff);
  scanC_kernel<<<SCAN_NB, 256, 0, stream>>>(cR, boff, rPtr, urR);
  scanA_kernel<<<SCAN_NB, 256, 0, stream>>>(cC, bsum);
  scanB_kernel<<<1, 256, 0, stream>>>(bsum, boff);
  scanC_kernel<<<SCAN_NB, 256, 0, stream>>>(cC, boff, cPtr, uC);
  sortscatter_kernel<<<edgeGrid, 256, 0, stream>>>(esrc, edst, dis, urR, uC,
                                                   cb8, cEnt);

  for (int k = 0; k < KS; ++k) {
    if (k == 0)
      adj_kernel<1><<<2 * NODE_NB, 256, 0, stream>>>(XHlo, XHhi, x, U, dis,
                                                     rPtr, cPtr, cEnt, cb8,
                                                     XB, XBh);
    else
      adj_kernel<0><<<2 * NODE_NB, 256, 0, stream>>>(XHlo, XHhi, x, U, dis,
                                                     rPtr, cPtr, cEnt, cb8,
                                                     XB, XBh);

    if (k == 0)
      zupd_kernel<1><<<NODE_NB, 256, 0, stream>>>(Z, XBh, dis, rPtr, cb8, U1);
    else
      zupd_kernel<0><<<NODE_NB, 256, 0, stream>>>(Z, XBh, dis, rPtr, cb8, U1);

    if (k == 0)
      cside_kernel<1, 0><<<NODE_NB, 256, 0, stream>>>(Z, XB, dis, cPtr, cEnt,
                                                      U1, U, out, XHlo, XHhi);
    else if (k == KS - 1)
      cside_kernel<0, 1><<<NODE_NB, 256, 0, stream>>>(Z, XB, dis, cPtr, cEnt,
                                                      U1, U, out, XHlo, XHhi);
    else
      cside_kernel<0, 0><<<NODE_NB, 256, 0, stream>>>(Z, XB, dis, cPtr, cEnt,
                                                      U1, U, out, XHlo, XHhi);
  }
}

// Round 9
// 1359.790 us; speedup vs baseline: 1.1383x; 1.1383x over previous
//
#include <hip/hip_runtime.h>
#include <hip/hip_fp16.h>
#include <math.h>

// Problem constants (match reference)
constexpr int NN = 50000;    // nodes
constexpr int NE = 800000;   // undirected edges E0
constexpr int KS = 10;       // iterations
constexpr float LAM = 3.0f;  // lambda

constexpr int SCAN_NB = (NN + 255) / 256;  // 196 scan blocks
constexpr int NODE_NB = NN * 64 / 256;     // 12500 one-wave-per-node blocks

// ---------------- precompute kernels ----------------

__global__ __launch_bounds__(256) void countRC_kernel(
    const int* __restrict__ src, const int* __restrict__ dst,
    int* __restrict__ cR, int* __restrict__ cC) {
  int e = blockIdx.x * 256 + threadIdx.x;
  if (e >= NE) return;
  int s = src[e], d = dst[e];
  int r = s > d ? s : d;
  int c = s > d ? d : s;
  atomicAdd(&cR[r], 1);
  atomicAdd(&cC[c], 1);
}

__global__ __launch_bounds__(256) void dis_kernel(
    const int* __restrict__ cR, const int* __restrict__ cC,
    float* __restrict__ dis) {
  int i = blockIdx.x * 256 + threadIdx.x;
  if (i < NN) dis[i] = 1.0f / sqrtf((float)(cR[i] + cC[i] + 1));
}

// fp16 interleaved shadow of x ([NN x 64], uint2 = 4 halves per lane-slot)
__global__ __launch_bounds__(256) void half_copy_kernel(
    const float* __restrict__ X, __half* __restrict__ XH) {
  int i = blockIdx.x * 256 + threadIdx.x;
  if (i >= NN * 16) return;
  float4 v = ((const float4*)X)[i];
  __half2 h0 = __floats2half2_rn(v.x, v.y);
  __half2 h1 = __floats2half2_rn(v.z, v.w);
  uint2 o;
  o.x = *(const unsigned*)&h0;
  o.y = *(const unsigned*)&h1;
  ((uint2*)XH)[i] = o;
}

// ---- hierarchical exclusive scan: A) block sums, B) scan sums, C) emit ----

__global__ __launch_bounds__(256) void scanA_kernel(
    const int* __restrict__ cnt, int* __restrict__ bsum) {
  __shared__ int sm[256];
  int t = threadIdx.x;
  int i = blockIdx.x * 256 + t;
  int v = (i < NN) ? cnt[i] : 0;
  sm[t] = v;
  __syncthreads();
  for (int off = 128; off > 0; off >>= 1) {
    if (t < off) sm[t] += sm[t + off];
    __syncthreads();
  }
  if (t == 0) bsum[blockIdx.x] = sm[0];
}

__global__ __launch_bounds__(256) void scanB_kernel(
    int* __restrict__ bsum, int* __restrict__ boff) {
  __shared__ int sm[256];
  int t = threadIdx.x;
  int v = (t < SCAN_NB) ? bsum[t] : 0;
  sm[t] = v;
  __syncthreads();
  for (int off = 1; off < 256; off <<= 1) {
    int a = (t >= off) ? sm[t - off] : 0;
    __syncthreads();
    sm[t] += a;
    __syncthreads();
  }
  if (t < SCAN_NB) boff[t] = sm[t] - v;  // exclusive
}

__global__ __launch_bounds__(256) void scanC_kernel(
    const int* __restrict__ cnt, const int* __restrict__ boff,
    int* __restrict__ ptr, int* __restrict__ cur) {
  __shared__ int sm[256];
  int t = threadIdx.x;
  int i = blockIdx.x * 256 + t;
  int v = (i < NN) ? cnt[i] : 0;
  sm[t] = v;
  __syncthreads();
  for (int off = 1; off < 256; off <<= 1) {
    int a = (t >= off) ? sm[t - off] : 0;
    __syncthreads();
    sm[t] += a;
    __syncthreads();
  }
  if (i < NN) {
    int ex = boff[blockIdx.x] + sm[t] - v;  // exclusive prefix
    ptr[i] = ex;
    cur[i] = ex;
    if (i == NN - 1) ptr[NN] = ex + v;
  }
}

// Counting-sort scatter: new edge id p = position in r-sorted order.
// cb8[p] = (c, dis[c]) 8B; c-side CSR entry (r, p) for node c.
__global__ __launch_bounds__(256) void sortscatter_kernel(
    const int* __restrict__ src, const int* __restrict__ dst,
    const float* __restrict__ dis,
    int* __restrict__ urR, int* __restrict__ uC,
    int2* __restrict__ cb8, int2* __restrict__ cEnt) {
  int e = blockIdx.x * 256 + threadIdx.x;
  if (e >= NE) return;
  int s = src[e], d = dst[e];
  int r = s > d ? s : d;
  int c = s > d ? d : s;
  int p = atomicAdd(&urR[r], 1);
  cb8[p] = make_int2(c, __float_as_int(dis[c]));
  int q = atomicAdd(&uC[c], 1);
  cEnt[q] = make_int2(r, p);
}

// ---------------- per-step kernels ----------------
// One wave (64 lanes) per node row; lanes split as 4 groups x 16.
// Lane l covers 4 feats (8B fp16); shfl_xor(16/32) folds the 4 groups.

// adj: y = 0.25*h + 0.75*(D^-1/2 (A+I) D^-1/2) xk ; XB = y - 0.25*U_old.
// Unified branch-free r-side/c-side walk, x4 unrolled (16 chains/wave);
// gathers from interleaved fp16 shadow XH. Writes XB fp32 + XBh fp16.
template <int FIRST>
__global__ __launch_bounds__(256) void adj_kernel(
    const __half* __restrict__ XH, const float* __restrict__ H,
    const float* __restrict__ U, const float* __restrict__ dis,
    const int* __restrict__ rPtr, const int* __restrict__ cPtr,
    const int2* __restrict__ cEnt, const int2* __restrict__ cb8,
    float* __restrict__ XB, __half* __restrict__ XBh) {
  int w = (int)((blockIdx.x * 256u + threadIdx.x) >> 6);
  if (w >= NN) return;
  int lane = threadIdx.x & 63;
  int g = lane >> 4, l = lane & 15;
  const uint2* XH2 = (const uint2*)XH;
  int rb = rPtr[w], lenR = rPtr[w + 1] - rb;
  int cb = cPtr[w], lenC = cPtr[w + 1] - cb;
  int total = lenR + lenC;
  int lr1 = lenR > 0 ? lenR - 1 : 0;
  int lc1 = lenC > 0 ? lenC - 1 : 0;
  float ax = 0.f, ay = 0.f, az = 0.f, aw = 0.f;

#define ADJ_FETCH(T, NB, WT)                                         \
  {                                                                  \
    int tr = (T) < lr1 ? (T) : lr1;                                  \
    int tc = (T) - lenR; tc = tc > 0 ? tc : 0; tc = tc < lc1 ? tc : lc1; \
    int2 rcv = cb8[rb + tr];                                         \
    int2 ce = cEnt[cb + tc];                                         \
    bool isR = (T) < lenR;                                           \
    NB = isR ? rcv.x : ce.x;                                         \
    WT = isR ? __int_as_float(rcv.y) : dis[ce.x];                    \
  }
#define ADJ_ACC(XV, W)                                               \
  {                                                                  \
    float2 p = __half22float2(*(const __half2*)&XV.x);               \
    float2 q = __half22float2(*(const __half2*)&XV.y);               \
    ax = fmaf(W, p.x, ax); ay = fmaf(W, p.y, ay);                    \
    az = fmaf(W, q.x, az); aw = fmaf(W, q.y, aw);                    \
  }

  int t = g;
  for (; t + 12 < total; t += 16) {
    int n0, n1, n2, n3; float w0, w1, w2, w3;
    ADJ_FETCH(t, n0, w0);
    ADJ_FETCH(t + 4, n1, w1);
    ADJ_FETCH(t + 8, n2, w2);
    ADJ_FETCH(t + 12, n3, w3);
    uint2 x0 = XH2[n0 * 16 + l];
    uint2 x1 = XH2[n1 * 16 + l];
    uint2 x2 = XH2[n2 * 16 + l];
    uint2 x3 = XH2[n3 * 16 + l];
    ADJ_ACC(x0, w0);
    ADJ_ACC(x1, w1);
    ADJ_ACC(x2, w2);
    ADJ_ACC(x3, w3);
  }
  for (; t < total; t += 4) {
    int n0; float w0;
    ADJ_FETCH(t, n0, w0);
    uint2 x0 = XH2[n0 * 16 + l];
    ADJ_ACC(x0, w0);
  }
#undef ADJ_FETCH
#undef ADJ_ACC

  ax += __shfl_xor(ax, 16, 64); ay += __shfl_xor(ay, 16, 64);
  az += __shfl_xor(az, 16, 64); aw += __shfl_xor(aw, 16, 64);
  ax += __shfl_xor(ax, 32, 64); ay += __shfl_xor(ay, 32, 64);
  az += __shfl_xor(az, 32, 64); aw += __shfl_xor(aw, 32, 64);
  if (g == 0) {
    float di = dis[w];
    int idx = w * 16 + l;
    uint2 xsu = XH2[idx];  // self term from fp16 shadow
    float2 xsa = __half22float2(*(const __half2*)&xsu.x);
    float2 xsb = __half22float2(*(const __half2*)&xsu.y);
    float4 h4 = ((const float4*)H)[idx];
    float4 y4;
    y4.x = 0.25f * h4.x + 0.75f * di * fmaf(di, xsa.x, ax);
    y4.y = 0.25f * h4.y + 0.75f * di * fmaf(di, xsa.y, ay);
    y4.z = 0.25f * h4.z + 0.75f * di * fmaf(di, xsb.x, az);
    y4.w = 0.25f * h4.w + 0.75f * di * fmaf(di, xsb.y, aw);
    float4 xb;
    if (FIRST) {
      xb = y4;
    } else {
      float4 u4 = ((const float4*)U)[idx];
      xb.x = y4.x - 0.25f * u4.x;
      xb.y = y4.y - 0.25f * u4.y;
      xb.z = y4.z - 0.25f * u4.z;
      xb.w = y4.w - 0.25f * u4.w;
    }
    ((float4*)XB)[idx] = xb;
    __half2 hb0 = __floats2half2_rn(xb.x, xb.y);
    __half2 hb1 = __floats2half2_rn(xb.z, xb.w);
    uint2 ob;
    ob.x = *(const unsigned*)&hb0;
    ob.y = *(const unsigned*)&hb1;
    ((uint2*)XBh)[idx] = ob;
  }
}

// zupd: per node w (skew-balanced pair mapping), walk contiguous r-side
// edge range: z' = proj_L21(z + 2*(dis[w]*xb[w] - b*xb[c])), write Z in
// place, accumulate U1[w] = sum_r z'. x2-unrolled dual z-chains per group
// (8 edges in flight per wave); 2*a*xw hoisted out of the loop.
template <int FIRST>
__global__ __launch_bounds__(256) void zupd_kernel(
    __half* __restrict__ Z, const __half* __restrict__ XBh,
    const float* __restrict__ dis,
    const int* __restrict__ rPtr, const int2* __restrict__ cb8,
    float* __restrict__ U1) {
  int i = (int)((blockIdx.x * 256u + threadIdx.x) >> 6);
  if (i >= NN) return;
  int w = (i & 1) ? (NN - 1 - (i >> 1)) : (i >> 1);  // heavy+light pairing
  int lane = threadIdx.x & 63;
  int g = lane >> 4, l = lane & 15;
  const uint2* X2 = (const uint2*)XBh;
  uint2* Z2 = (uint2*)Z;
  int rb = rPtr[w], re = rPtr[w + 1];
  float a2 = 2.0f * dis[w];
  uint2 xwu = X2[w * 16 + l];
  float2 xwa = __half22float2(*(const __half2*)&xwu.x);
  float2 xwb = __half22float2(*(const __half2*)&xwu.y);
  float tx = a2 * xwa.x, ty = a2 * xwa.y;
  float tz = a2 * xwb.x, tw = a2 * xwb.y;
  float sx = 0.f, sy = 0.f, sz = 0.f, sw = 0.f;

#define Z_PROC(E, CV, XCU, ZU)                                       \
  {                                                                  \
    float b2 = 2.0f * __int_as_float(CV.y);                          \
    float2 xca = __half22float2(*(const __half2*)&XCU.x);            \
    float2 xcb = __half22float2(*(const __half2*)&XCU.y);            \
    float zx, zy, zz, zw;                                            \
    if (FIRST) {                                                     \
      zx = zy = zz = zw = 0.f;                                       \
    } else {                                                         \
      float2 f0 = __half22float2(*(const __half2*)&ZU.x);            \
      float2 f1 = __half22float2(*(const __half2*)&ZU.y);            \
      zx = f0.x; zy = f0.y; zz = f1.x; zw = f1.y;                    \
    }                                                                \
    zx += tx - b2 * xca.x;                                           \
    zy += ty - b2 * xca.y;                                           \
    zz += tz - b2 * xcb.x;                                           \
    zw += tw - b2 * xcb.y;                                           \
    float ss = zx * zx + zy * zy + zz * zz + zw * zw;                \
    ss += __shfl_xor(ss, 1, 64);                                     \
    ss += __shfl_xor(ss, 2, 64);                                     \
    ss += __shfl_xor(ss, 4, 64);                                     \
    ss += __shfl_xor(ss, 8, 64);                                     \
    float rn = sqrtf(ss);                                            \
    float sc = (rn > LAM) ? (LAM / rn) : 1.0f;                       \
    zx *= sc; zy *= sc; zz *= sc; zw *= sc;                          \
    __half2 o0 = __floats2half2_rn(zx, zy);                          \
    __half2 o1 = __floats2half2_rn(zz, zw);                          \
    uint2 outu;                                                      \
    outu.x = *(const unsigned*)&o0;                                  \
    outu.y = *(const unsigned*)&o1;                                  \
    Z2[(E) * 16 + l] = outu;                                         \
    sx += zx; sy += zy; sz += zz; sw += zw;                          \
  }

  int e = rb + g;
  for (; e + 4 < re; e += 8) {
    int2 cv0 = cb8[e];
    int2 cv1 = cb8[e + 4];
    uint2 xc0 = X2[cv0.x * 16 + l];
    uint2 xc1 = X2[cv1.x * 16 + l];
    uint2 zu0, zu1;
    if (!FIRST) {
      zu0 = Z2[e * 16 + l];
      zu1 = Z2[(e + 4) * 16 + l];
    }
    Z_PROC(e, cv0, xc0, zu0);
    Z_PROC(e + 4, cv1, xc1, zu1);
  }
  if (e < re) {
    int2 cv0 = cb8[e];
    uint2 xc0 = X2[cv0.x * 16 + l];
    uint2 zu0;
    if (!FIRST) zu0 = Z2[e * 16 + l];
    Z_PROC(e, cv0, xc0, zu0);
  }
#undef Z_PROC

  sx += __shfl_xor(sx, 16, 64); sy += __shfl_xor(sy, 16, 64);
  sz += __shfl_xor(sz, 16, 64); sw += __shfl_xor(sw, 16, 64);
  sx += __shfl_xor(sx, 32, 64); sy += __shfl_xor(sy, 32, 64);
  sz += __shfl_xor(sz, 32, 64); sw += __shfl_xor(sw, 32, 64);
  if (g == 0) {
    ((float4*)U1)[w * 16 + l] = make_float4(sx, sy, sz, sw);
  }
}

// cside: csum = sum_{c-side} z' (random gather, x4 unrolled);
// u = dis*(U1 - csum); y = XB + 0.25*U_old; xnew = y - 0.25*u;
// U <- u; XH <- fp16(xnew) (LAST: write fp32 out instead).
template <int FIRST, int LAST>
__global__ __launch_bounds__(256) void cside_kernel(
    const __half* __restrict__ Z, const float* __restrict__ XB,
    const float* __restrict__ dis,
    const int* __restrict__ cPtr, const int2* __restrict__ cEnt,
    const float* __restrict__ U1, float* __restrict__ U,
    float* __restrict__ Xout, __half* __restrict__ XH) {
  int i = (int)((blockIdx.x * 256u + threadIdx.x) >> 6);
  if (i >= NN) return;
  int w = (i & 1) ? (NN - 1 - (i >> 1)) : (i >> 1);  // heavy+light pairing
  int lane = threadIdx.x & 63;
  int g = lane >> 4, l = lane & 15;
  const uint2* Z2 = (const uint2*)Z;
  int cb = cPtr[w], ce = cPtr[w + 1];
  float sx = 0.f, sy = 0.f, sz = 0.f, sw = 0.f;
  int j = cb + g;
  for (; j + 12 < ce; j += 16) {
    int e0 = cEnt[j].y;
    int e1 = cEnt[j + 4].y;
    int e2 = cEnt[j + 8].y;
    int e3 = cEnt[j + 12].y;
    uint2 zu0 = Z2[e0 * 16 + l];
    uint2 zu1 = Z2[e1 * 16 + l];
    uint2 zu2 = Z2[e2 * 16 + l];
    uint2 zu3 = Z2[e3 * 16 + l];
    float2 a0 = __half22float2(*(const __half2*)&zu0.x);
    float2 b0 = __half22float2(*(const __half2*)&zu0.y);
    float2 a1 = __half22float2(*(const __half2*)&zu1.x);
    float2 b1 = __half22float2(*(const __half2*)&zu1.y);
    float2 a2 = __half22float2(*(const __half2*)&zu2.x);
    float2 b2 = __half22float2(*(const __half2*)&zu2.y);
    float2 a3 = __half22float2(*(const __half2*)&zu3.x);
    float2 b3 = __half22float2(*(const __half2*)&zu3.y);
    sx += a0.x + a1.x + a2.x + a3.x;
    sy += a0.y + a1.y + a2.y + a3.y;
    sz += b0.x + b1.x + b2.x + b3.x;
    sw += b0.y + b1.y + b2.y + b3.y;
  }
  for (; j < ce; j += 4) {
    int e0 = cEnt[j].y;
    uint2 zu0 = Z2[e0 * 16 + l];
    float2 a0 = __half22float2(*(const __half2*)&zu0.x);
    float2 b0 = __half22float2(*(const __half2*)&zu0.y);
    sx += a0.x; sy += a0.y; sz += b0.x; sw += b0.y;
  }
  sx += __shfl_xor(sx, 16, 64); sy += __shfl_xor(sy, 16, 64);
  sz += __shfl_xor(sz, 16, 64); sw += __shfl_xor(sw, 16, 64);
  sx += __shfl_xor(sx, 32, 64); sy += __shfl_xor(sy, 32, 64);
  sz += __shfl_xor(sz, 32, 64); sw += __shfl_xor(sw, 32, 64);
  if (g == 0) {
    float di = dis[w];
    int idx = w * 16 + l;
    float4 u1 = ((const float4*)U1)[idx];
    float4 u;
    u.x = di * (u1.x - sx);
    u.y = di * (u1.y - sy);
    u.z = di * (u1.z - sz);
    u.w = di * (u1.w - sw);
    float4 xb = ((const float4*)XB)[idx];
    float4 y4;
    if (FIRST) {
      y4 = xb;  // U_old == 0
    } else {
      float4 uo = ((const float4*)U)[idx];
      y4.x = xb.x + 0.25f * uo.x;
      y4.y = xb.y + 0.25f * uo.y;
      y4.z = xb.z + 0.25f * uo.z;
      y4.w = xb.w + 0.25f * uo.w;
    }
    float4 o;
    o.x = y4.x - 0.25f * u.x;
    o.y = y4.y - 0.25f * u.y;
    o.z = y4.z - 0.25f * u.z;
    o.w = y4.w - 0.25f * u.w;
    if (LAST) {
      ((float4*)Xout)[idx] = o;
    } else {
      ((float4*)U)[idx] = u;
      __half2 h0 = __floats2half2_rn(o.x, o.y);
      __half2 h1 = __floats2half2_rn(o.z, o.w);
      uint2 oh;
      oh.x = *(const unsigned*)&h0;
      oh.y = *(const unsigned*)&h1;
      ((uint2*)XH)[idx] = oh;
    }
  }
}

// ---------------- launch ----------------

extern "C" void kernel_launch(void* const* d_in, const int* in_sizes, int n_in,
                              void* d_out, int out_size, void* d_ws, size_t ws_size,
                              hipStream_t stream) {
  const float* x  = (const float*)d_in[0];
  const int* esrc = (const int*)d_in[1];
  const int* edst = (const int*)d_in[2];
  float* out = (float*)d_out;

  char* base = (char*)d_ws;
  size_t off = 0;
  auto carve = [&](size_t bytes) -> void* {
    void* p = base + off;
    off += (bytes + 255) & ~(size_t)255;
    return p;
  };
  __half* Z   = (__half*)carve((size_t)NE * 64 * 2);  // 102.4 MB carry z
  float* XB   = (float*)carve((size_t)NN * 64 * 4);   // x_bar fp32 master
  float* U    = (float*)carve((size_t)NN * 64 * 4);   // incT(z) carry
  float* U1   = (float*)carve((size_t)NN * 64 * 4);   // r-side partial sums
  __half* XH  = (__half*)carve((size_t)NN * 64 * 2);  // xk fp16 shadow
  __half* XBh = (__half*)carve((size_t)NN * 64 * 2);  // x_bar fp16 shadow
  float* dis = (float*)carve((size_t)NN * 4);
  int* cR  = (int*)carve((size_t)NN * 4);
  int* cC  = (int*)carve((size_t)NN * 4);
  int* rPtr = (int*)carve((size_t)(NN + 1) * 4);
  int* cPtr = (int*)carve((size_t)(NN + 1) * 4);
  int* urR = (int*)carve((size_t)NN * 4);
  int* uC  = (int*)carve((size_t)NN * 4);
  int* bsum = (int*)carve((size_t)SCAN_NB * 4);
  int* boff = (int*)carve((size_t)SCAN_NB * 4);
  int2* cb8  = (int2*)carve((size_t)(NE + 4) * 8);  // (c, dis[c]) sorted by r
  int2* cEnt = (int2*)carve((size_t)(NE + 4) * 8);  // (r, p) c-side CSR
  (void)ws_size; (void)in_sizes; (void)n_in; (void)out_size;

  hipMemsetAsync(cR, 0, NN * 4, stream);
  hipMemsetAsync(cC, 0, NN * 4, stream);

  const int edgeGrid = (NE + 255) / 256;
  countRC_kernel<<<edgeGrid, 256, 0, stream>>>(esrc, edst, cR, cC);
  dis_kernel<<<(NN + 255) / 256, 256, 0, stream>>>(cR, cC, dis);
  half_copy_kernel<<<(NN * 16 + 255) / 256, 256, 0, stream>>>(x, XH);
  scanA_kernel<<<SCAN_NB, 256, 0, stream>>>(cR, bsum);
  scanB_kernel<<<1, 256, 0, stream>>>(bsum, boff);
  scanC_kernel<<<SCAN_NB, 256, 0, stream>>>(cR, boff, rPtr, urR);
  scanA_kernel<<<SCAN_NB, 256, 0, stream>>>(cC, bsum);
  scanB_kernel<<<1, 256, 0, stream>>>(bsum, boff);
  scanC_kernel<<<SCAN_NB, 256, 0, stream>>>(cC, boff, cPtr, uC);
  sortscatter_kernel<<<edgeGrid, 256, 0, stream>>>(esrc, edst, dis, urR, uC,
                                                   cb8, cEnt);

  for (int k = 0; k < KS; ++k) {
    if (k == 0)
      adj_kernel<1><<<NODE_NB, 256, 0, stream>>>(XH, x, U, dis, rPtr, cPtr,
                                                 cEnt, cb8, XB, XBh);
    else
      adj_kernel<0><<<NODE_NB, 256, 0, stream>>>(XH, x, U, dis, rPtr, cPtr,
                                                 cEnt, cb8, XB, XBh);

    if (k == 0)
      zupd_kernel<1><<<NODE_NB, 256, 0, stream>>>(Z, XBh, dis, rPtr, cb8, U1);
    else
      zupd_kernel<0><<<NODE_NB, 256, 0, stream>>>(Z, XBh, dis, rPtr, cb8, U1);

    if (k == 0)
      cside_kernel<1, 0><<<NODE_NB, 256, 0, stream>>>(Z, XB, dis, cPtr, cEnt,
                                                      U1, U, out, XH);
    else if (k == KS - 1)
      cside_kernel<0, 1><<<NODE_NB, 256, 0, stream>>>(Z, XB, dis, cPtr, cEnt,
                                                      U1, U, out, XH);
    else
      cside_kernel<0, 0><<<NODE_NB, 256, 0, stream>>>(Z, XB, dis, cPtr, cEnt,
                                                      U1, U, out, XH);
  }
}